// Round 2
// baseline (1987.109 us; speedup 1.0000x reference)
//
#include <hip/hip_runtime.h>

#define NN   20000   // nodes
#define NE   160000  // edges
#define HD   32      // hidden / in dim
#define EFD  95      // edge feature dim
#define EHD  64      // edge hidden dim
#define NG   64      // graphs
#define EPSF 1e-5f

// ---------------------------------------------------------------- zero fill
__global__ __launch_bounds__(256) void zero_kernel(float* __restrict__ p, int n) {
    int i = blockIdx.x * 256 + threadIdx.x;
    if (i < n) p[i] = 0.f;
}

// ---------------------------------------------------------------- edge MLP: h = relu(ea @ W1 + b1)
// grid (NE/256, 2). Thread computes 32 of the 64 h outputs for one edge.
// W1/b1 addresses are thread-uniform -> s_load; FMA with SGPR operand.
__global__ __launch_bounds__(256) void edge_mlp_kernel(
    const float* __restrict__ ea,    // NE x 95
    const float* __restrict__ W1,    // 95 x 64
    const float* __restrict__ b1,    // 64
    float*       __restrict__ h)     // NE x 64 (out)
{
    const int e  = blockIdx.x * 256 + threadIdx.x;
    const int hh = blockIdx.y * 32;          // wave-uniform half select

    float acc[32];
    #pragma unroll
    for (int k = 0; k < 32; ++k) acc[k] = b1[hh + k];

    const float* er = ea + e * EFD;
    #pragma unroll 2
    for (int j = 0; j < EFD; ++j) {
        const float ej = er[j];
        const float* w1r = W1 + j * EHD + hh;   // uniform -> s_load
        #pragma unroll
        for (int k = 0; k < 32; ++k)
            acc[k] = fmaf(ej, w1r[k], acc[k]);
    }

    float* hr = h + e * EHD + hh;               // 16B aligned (e*256B + hh*128B)
    #pragma unroll
    for (int k4 = 0; k4 < 8; ++k4) {
        float4 v;
        v.x = fmaxf(acc[k4 * 4 + 0], 0.f);
        v.y = fmaxf(acc[k4 * 4 + 1], 0.f);
        v.z = fmaxf(acc[k4 * 4 + 2], 0.f);
        v.w = fmaxf(acc[k4 * 4 + 3], 0.f);
        *reinterpret_cast<float4*>(hr + k4 * 4) = v;
    }
}

// ---------------------------------------------------------------- fused NNConv contraction + scatter
// grid (NE/256, 2). Thread computes 16 of 32 msg outputs for one edge:
//   msg[o] = sum_{kh,i} h[kh]*xs[i]*W2[kh][i*32+o] + sum_i xs[i]*b2[i*32+o]
// then atomically scatters into agg[dst]. W2/b2 thread-uniform -> s_load.
// LDS-free; ~60 VGPR; occupancy grid-bound at ~4.9 waves/SIMD.
__global__ __launch_bounds__(256) void nnconv_kernel(
    const float* __restrict__ xin,   // NN x 32
    const int*   __restrict__ src,   // NE
    const int*   __restrict__ dst,   // NE
    const float* __restrict__ h,     // NE x 64 (relu'd)
    const float* __restrict__ W2,    // 64 x 1024
    const float* __restrict__ b2,    // 1024
    float*       __restrict__ agg)   // NN x 32, pre-zeroed
{
    const int e  = blockIdx.x * 256 + threadIdx.x;
    const int oh = blockIdx.y * 16;          // wave-uniform output-half select
    const int s = src[e];
    const int d = dst[e];

    // x_src row (rows are 128B aligned)
    float xs[HD];
    {
        const float* xr = xin + s * HD;
        #pragma unroll
        for (int i = 0; i < HD; i += 4) {
            const float4 v = *reinterpret_cast<const float4*>(xr + i);
            xs[i] = v.x; xs[i + 1] = v.y; xs[i + 2] = v.z; xs[i + 3] = v.w;
        }
    }

    float acc[16];
    #pragma unroll
    for (int o = 0; o < 16; ++o) acc[o] = 0.f;

    const float* hrow = h + e * EHD;
    #pragma unroll 1
    for (int kh = 0; kh < EHD; ++kh) {
        const float hk = hrow[kh];               // 1 load per 512 FMA
        const float* w2k = W2 + kh * (HD * HD) + oh;   // uniform -> s_load
        #pragma unroll
        for (int i = 0; i < HD; ++i) {
            const float p = hk * xs[i];
            #pragma unroll
            for (int o = 0; o < 16; ++o)
                acc[o] = fmaf(p, w2k[i * HD + o], acc[o]);
        }
    }

    // bias term: acc[o] += xs[i] * b2[i*32 + oh + o]
    #pragma unroll 1
    for (int i = 0; i < HD; ++i) {
        const float xi = xs[i];
        const float* b2r = b2 + i * HD + oh;     // uniform -> s_load
        #pragma unroll
        for (int o = 0; o < 16; ++o)
            acc[o] = fmaf(xi, b2r[o], acc[o]);
    }

    float* ar = agg + d * HD + oh;
    #pragma unroll
    for (int o = 0; o < 16; ++o)
        unsafeAtomicAdd(ar + o, acc[o]);         // native global_atomic_add_f32
}

// ---------------------------------------------------------------- node update: agg + x@root + bias -> BN -> relu
__global__ __launch_bounds__(256) void node_update_kernel(
    const float* __restrict__ agg, const float* __restrict__ xin,
    const float* __restrict__ root, const float* __restrict__ bias,
    const float* __restrict__ bg, const float* __restrict__ bb,
    const float* __restrict__ brm, const float* __restrict__ brv,
    float* __restrict__ xout)
{
    const int gid = blockIdx.x * 256 + threadIdx.x;   // grid = NN*32/256
    const int n = gid >> 5, o = gid & 31;
    const float* xr = xin + n * HD;
    float a = agg[gid];
    #pragma unroll
    for (int i = 0; i < HD; ++i)
        a = fmaf(xr[i], root[i * HD + o], a);
    a += bias[o];
    a = (a - brm[o]) * rsqrtf(brv[o] + EPSF) * bg[o] + bb[o];
    xout[gid] = fmaxf(a, 0.f);
}

// ---------------------------------------------------------------- segment max pool (x >= 0 after relu; g zero-init)
__global__ __launch_bounds__(256) void pool_kernel(
    const float* __restrict__ x, const int* __restrict__ batch,
    float* __restrict__ g)
{
    const int gid = blockIdx.x * 256 + threadIdx.x;
    const int n = gid >> 5, o = gid & 31;
    const float v = x[gid];
    // v >= 0: int ordering == float ordering and 0-init is the identity
    atomicMax(reinterpret_cast<int*>(g) + batch[n] * HD + o, __float_as_int(v));
}

// ---------------------------------------------------------------- MLP head: relu(g@lin1+b) @ lin2 + b
__global__ __launch_bounds__(64) void head_kernel(
    const float* __restrict__ g, const float* __restrict__ l1W,
    const float* __restrict__ l1b, const float* __restrict__ l2W,
    const float* __restrict__ l2b, float* __restrict__ out)
{
    const int gr = threadIdx.x;         // 64 threads, one per graph
    const float* grow = g + gr * HD;
    float hv[HD];
    #pragma unroll
    for (int o = 0; o < HD; ++o) hv[o] = l1b[o];
    #pragma unroll
    for (int i = 0; i < HD; ++i) {
        const float gi = grow[i];
        #pragma unroll
        for (int o = 0; o < HD; ++o)
            hv[o] = fmaf(gi, l1W[i * HD + o], hv[o]);
    }
    float o0 = l2b[0], o1 = l2b[1];
    #pragma unroll
    for (int o = 0; o < HD; ++o) {
        const float r = fmaxf(hv[o], 0.f);
        o0 = fmaf(r, l2W[o * 2 + 0], o0);
        o1 = fmaf(r, l2W[o * 2 + 1], o1);
    }
    out[gr * 2 + 0] = o0;
    out[gr * 2 + 1] = o1;
}

// ---------------------------------------------------------------- launcher
extern "C" void kernel_launch(void* const* d_in, const int* in_sizes, int n_in,
                              void* d_out, int out_size, void* d_ws, size_t ws_size,
                              hipStream_t stream)
{
    const float* x     = (const float*)d_in[0];
    const int*   esrc  = (const int*)  d_in[1];
    const int*   edst  = (const int*)  d_in[2];
    const float* eattr = (const float*)d_in[3];
    const int*   batch = (const int*)  d_in[4];

    const float* c0W1   = (const float*)d_in[5];
    const float* c0b1   = (const float*)d_in[6];
    const float* c0W2   = (const float*)d_in[7];
    const float* c0b2   = (const float*)d_in[8];
    const float* c0root = (const float*)d_in[9];
    const float* c0bias = (const float*)d_in[10];
    const float* bn0g   = (const float*)d_in[11];
    const float* bn0b   = (const float*)d_in[12];
    const float* bn0rm  = (const float*)d_in[13];
    const float* bn0rv  = (const float*)d_in[14];

    const float* c1W1   = (const float*)d_in[15];
    const float* c1b1   = (const float*)d_in[16];
    const float* c1W2   = (const float*)d_in[17];
    const float* c1b2   = (const float*)d_in[18];
    const float* c1root = (const float*)d_in[19];
    const float* c1bias = (const float*)d_in[20];
    const float* bn1g   = (const float*)d_in[21];
    const float* bn1b   = (const float*)d_in[22];
    const float* bn1rm  = (const float*)d_in[23];
    const float* bn1rv  = (const float*)d_in[24];

    const float* l1W = (const float*)d_in[25];
    const float* l1b = (const float*)d_in[26];
    const float* l2W = (const float*)d_in[27];
    const float* l2b = (const float*)d_in[28];

    // workspace layout (floats): [h: 10.24M][agg: 640K][gbuf: 2048][x1: 640K][x2: 640K]
    float* ws   = (float*)d_ws;
    float* hbuf = ws;                       // NE*64 = 10,240,000
    float* agg  = ws + 10240000;            // NN*32 =    640,000
    float* gbuf = ws + 10880000;            // NG*32 =      2,048
    float* x1   = ws + 10882048;            // NN*32
    float* x2   = ws + 11522048;            // NN*32
    // total: 12,162,048 floats ~= 48.7 MB

    const dim3 egrid(NE / 256, 2);

    // zero agg+gbuf (contiguous, 642048 = 2508*256)
    zero_kernel<<<2508, 256, 0, stream>>>(agg, 642048);

    // layer 0
    edge_mlp_kernel<<<egrid, 256, 0, stream>>>(eattr, c0W1, c0b1, hbuf);
    nnconv_kernel<<<egrid, 256, 0, stream>>>(x, esrc, edst, hbuf, c0W2, c0b2, agg);
    node_update_kernel<<<NN * HD / 256, 256, 0, stream>>>(agg, x, c0root, c0bias,
                                                          bn0g, bn0b, bn0rm, bn0rv, x1);
    // layer 1
    zero_kernel<<<2500, 256, 0, stream>>>(agg, 640000);
    edge_mlp_kernel<<<egrid, 256, 0, stream>>>(eattr, c1W1, c1b1, hbuf);
    nnconv_kernel<<<egrid, 256, 0, stream>>>(x1, esrc, edst, hbuf, c1W2, c1b2, agg);
    node_update_kernel<<<NN * HD / 256, 256, 0, stream>>>(agg, x1, c1root, c1bias,
                                                          bn1g, bn1b, bn1rm, bn1rv, x2);
    // pool + head
    pool_kernel<<<NN * HD / 256, 256, 0, stream>>>(x2, batch, gbuf);
    head_kernel<<<1, 64, 0, stream>>>(gbuf, l1W, l1b, l2W, l2b, (float*)d_out);
}

// Round 3
// 1646.635 us; speedup vs baseline: 1.2068x; 1.2068x over previous
//
#include <hip/hip_runtime.h>

#define NN   20000   // nodes
#define NE   160000  // edges
#define HD   32      // hidden / in dim
#define EFD  95      // edge feature dim
#define EHD  64      // edge hidden dim
#define NG   64      // graphs
#define EPSF 1e-5f

// ---------------------------------------------------------------- zero fill
__global__ __launch_bounds__(256) void zero_kernel(float* __restrict__ p, int n) {
    int i = blockIdx.x * 256 + threadIdx.x;
    if (i < n) p[i] = 0.f;
}

// ---------------------------------------------------------------- CSR build: histogram of dst
__global__ __launch_bounds__(256) void hist_kernel(const int* __restrict__ dst,
                                                   int* __restrict__ hist) {
    const int e = blockIdx.x * 256 + threadIdx.x;   // grid exactly NE/256
    atomicAdd(&hist[dst[e]], 1);
}

// ---------------------------------------------------------------- CSR build: exclusive scan (single block)
// 1024 threads x 20 elements = 20480 >= NN. Writes rowptr[0..NN] and cursor.
__global__ __launch_bounds__(1024) void scan_kernel(const int* __restrict__ hist,
                                                    int* __restrict__ rowptr,
                                                    int* __restrict__ cursor) {
    __shared__ int part[1024];
    const int t = threadIdx.x;
    const int base = t * 20;
    int s = 0;
    #pragma unroll
    for (int k = 0; k < 20; ++k) {
        const int idx = base + k;
        if (idx < NN) s += hist[idx];
    }
    part[t] = s;
    __syncthreads();
    // Hillis-Steele inclusive scan over 1024 partials
    for (int off = 1; off < 1024; off <<= 1) {
        int v = 0;
        if (t >= off) v = part[t - off];
        __syncthreads();
        if (t >= off) part[t] += v;
        __syncthreads();
    }
    int run = part[t] - s;   // exclusive offset for this chunk
    #pragma unroll
    for (int k = 0; k < 20; ++k) {
        const int idx = base + k;
        if (idx < NN) {
            rowptr[idx] = run;
            cursor[idx] = run;
            run += hist[idx];
        }
    }
    if (t == 0) rowptr[NN] = NE;
}

// ---------------------------------------------------------------- CSR build: stable-ish scatter -> sortpos
__global__ __launch_bounds__(256) void scatter_kernel(const int* __restrict__ dst,
                                                      int* __restrict__ cursor,
                                                      int* __restrict__ sortpos) {
    const int e = blockIdx.x * 256 + threadIdx.x;
    sortpos[e] = atomicAdd(&cursor[dst[e]], 1);
}

// ---------------------------------------------------------------- edge MLP: hT[k][e] = relu(ea @ W1 + b1)
// grid (NE/256, 2). Thread computes 32 of 64 h outputs for one edge.
// W1/b1 thread-uniform -> s_load. Output stored TRANSPOSED (coalesced per k).
__global__ __launch_bounds__(256) void edge_mlp_kernel(
    const float* __restrict__ ea,    // NE x 95
    const float* __restrict__ W1,    // 95 x 64
    const float* __restrict__ b1,    // 64
    float*       __restrict__ hT)    // EHD x NE (out, transposed)
{
    const int e  = blockIdx.x * 256 + threadIdx.x;
    const int hh = blockIdx.y * 32;          // wave-uniform half select

    float acc[32];
    #pragma unroll
    for (int k = 0; k < 32; ++k) acc[k] = b1[hh + k];

    const float* er = ea + e * EFD;
    #pragma unroll 2
    for (int j = 0; j < EFD; ++j) {
        const float ej = er[j];
        const float* w1r = W1 + j * EHD + hh;   // uniform -> s_load
        #pragma unroll
        for (int k = 0; k < 32; ++k)
            acc[k] = fmaf(ej, w1r[k], acc[k]);
    }

    #pragma unroll
    for (int k = 0; k < 32; ++k)
        hT[(hh + k) * NE + e] = fmaxf(acc[k], 0.f);   // coalesced across lanes
}

// ---------------------------------------------------------------- NNConv contraction, atomic-free
// grid (NE/64, 2), block 64 (5000 waves ~ 4.9/SIMD). Thread computes 16 of 32
// msg outputs for one edge and stores them at the dst-sorted slot sortpos[e].
//   msg[o] = sum_{kh,i} hT[kh][e]*xs[i]*W2[kh][i*32+o] + sum_i xs[i]*b2[i*32+o]
// W2/b2 thread-uniform -> s_load broadcast across the wave.
__global__ __launch_bounds__(64) void nnconv_kernel(
    const float* __restrict__ xin,     // NN x 32
    const int*   __restrict__ src,     // NE
    const int*   __restrict__ sortpos, // NE
    const float* __restrict__ hT,      // EHD x NE (relu'd)
    const float* __restrict__ W2,      // 64 x 1024
    const float* __restrict__ b2,      // 1024
    float*       __restrict__ msg)     // NE x 32, dst-sorted rows
{
    const int e  = blockIdx.x * 64 + threadIdx.x;
    const int oh = blockIdx.y * 16;          // wave-uniform output-half select
    const int s  = src[e];
    const int sp = sortpos[e];

    // x_src row (rows are 128B aligned)
    float xs[HD];
    {
        const float* xr = xin + s * HD;
        #pragma unroll
        for (int i = 0; i < HD; i += 4) {
            const float4 v = *reinterpret_cast<const float4*>(xr + i);
            xs[i] = v.x; xs[i + 1] = v.y; xs[i + 2] = v.z; xs[i + 3] = v.w;
        }
    }

    float acc[16];
    #pragma unroll
    for (int o = 0; o < 16; ++o) acc[o] = 0.f;

    #pragma unroll 1
    for (int kh = 0; kh < EHD; ++kh) {
        const float hk = hT[kh * NE + e];              // coalesced, 1 load / 512 FMA
        const float* w2k = W2 + kh * (HD * HD) + oh;   // uniform -> s_load
        #pragma unroll
        for (int i = 0; i < HD; ++i) {
            const float p = hk * xs[i];
            #pragma unroll
            for (int o = 0; o < 16; ++o)
                acc[o] = fmaf(p, w2k[i * HD + o], acc[o]);
        }
    }

    // bias term: acc[o] += xs[i] * b2[i*32 + oh + o]
    #pragma unroll 1
    for (int i = 0; i < HD; ++i) {
        const float xi = xs[i];
        const float* b2r = b2 + i * HD + oh;     // uniform -> s_load
        #pragma unroll
        for (int o = 0; o < 16; ++o)
            acc[o] = fmaf(xi, b2r[o], acc[o]);
    }

    // store to dst-sorted slot: full 64B line per half, no RMW, no atomics
    float* mr = msg + sp * HD + oh;
    #pragma unroll
    for (int q = 0; q < 4; ++q) {
        float4 v;
        v.x = acc[q * 4 + 0]; v.y = acc[q * 4 + 1];
        v.z = acc[q * 4 + 2]; v.w = acc[q * 4 + 3];
        *reinterpret_cast<float4*>(mr + q * 4) = v;
    }
}

// ---------------------------------------------------------------- fused CSR-reduce + root GEMV + BN + relu
__global__ __launch_bounds__(256) void node_update_kernel(
    const int*   __restrict__ rowptr, const float* __restrict__ msg,
    const float* __restrict__ xin,
    const float* __restrict__ root, const float* __restrict__ bias,
    const float* __restrict__ bg, const float* __restrict__ bb,
    const float* __restrict__ brm, const float* __restrict__ brv,
    float* __restrict__ xout)
{
    const int gid = blockIdx.x * 256 + threadIdx.x;   // grid = NN*32/256
    const int n = gid >> 5, o = gid & 31;

    float a = 0.f;
    const int j0 = rowptr[n], j1 = rowptr[n + 1];
    for (int j = j0; j < j1; ++j)                     // mean 8 iters, coalesced in o
        a += msg[j * HD + o];

    const float* xr = xin + n * HD;
    #pragma unroll
    for (int i = 0; i < HD; ++i)
        a = fmaf(xr[i], root[i * HD + o], a);
    a += bias[o];
    a = (a - brm[o]) * rsqrtf(brv[o] + EPSF) * bg[o] + bb[o];
    xout[gid] = fmaxf(a, 0.f);
}

// ---------------------------------------------------------------- segment max pool (x >= 0 after relu; g zero-init)
__global__ __launch_bounds__(256) void pool_kernel(
    const float* __restrict__ x, const int* __restrict__ batch,
    float* __restrict__ g)
{
    const int gid = blockIdx.x * 256 + threadIdx.x;
    const int n = gid >> 5, o = gid & 31;
    const float v = x[gid];
    // v >= 0: int ordering == float ordering and 0-init is the identity
    atomicMax(reinterpret_cast<int*>(g) + batch[n] * HD + o, __float_as_int(v));
}

// ---------------------------------------------------------------- MLP head: relu(g@lin1+b) @ lin2 + b
__global__ __launch_bounds__(64) void head_kernel(
    const float* __restrict__ g, const float* __restrict__ l1W,
    const float* __restrict__ l1b, const float* __restrict__ l2W,
    const float* __restrict__ l2b, float* __restrict__ out)
{
    const int gr = threadIdx.x;         // 64 threads, one per graph
    const float* grow = g + gr * HD;
    float hv[HD];
    #pragma unroll
    for (int o = 0; o < HD; ++o) hv[o] = l1b[o];
    #pragma unroll
    for (int i = 0; i < HD; ++i) {
        const float gi = grow[i];
        #pragma unroll
        for (int o = 0; o < HD; ++o)
            hv[o] = fmaf(gi, l1W[i * HD + o], hv[o]);
    }
    float o0 = l2b[0], o1 = l2b[1];
    #pragma unroll
    for (int o = 0; o < HD; ++o) {
        const float r = fmaxf(hv[o], 0.f);
        o0 = fmaf(r, l2W[o * 2 + 0], o0);
        o1 = fmaf(r, l2W[o * 2 + 1], o1);
    }
    out[gr * 2 + 0] = o0;
    out[gr * 2 + 1] = o1;
}

// ---------------------------------------------------------------- launcher
extern "C" void kernel_launch(void* const* d_in, const int* in_sizes, int n_in,
                              void* d_out, int out_size, void* d_ws, size_t ws_size,
                              hipStream_t stream)
{
    const float* x     = (const float*)d_in[0];
    const int*   esrc  = (const int*)  d_in[1];
    const int*   edst  = (const int*)  d_in[2];
    const float* eattr = (const float*)d_in[3];
    const int*   batch = (const int*)  d_in[4];

    const float* c0W1   = (const float*)d_in[5];
    const float* c0b1   = (const float*)d_in[6];
    const float* c0W2   = (const float*)d_in[7];
    const float* c0b2   = (const float*)d_in[8];
    const float* c0root = (const float*)d_in[9];
    const float* c0bias = (const float*)d_in[10];
    const float* bn0g   = (const float*)d_in[11];
    const float* bn0b   = (const float*)d_in[12];
    const float* bn0rm  = (const float*)d_in[13];
    const float* bn0rv  = (const float*)d_in[14];

    const float* c1W1   = (const float*)d_in[15];
    const float* c1b1   = (const float*)d_in[16];
    const float* c1W2   = (const float*)d_in[17];
    const float* c1b2   = (const float*)d_in[18];
    const float* c1root = (const float*)d_in[19];
    const float* c1bias = (const float*)d_in[20];
    const float* bn1g   = (const float*)d_in[21];
    const float* bn1b   = (const float*)d_in[22];
    const float* bn1rm  = (const float*)d_in[23];
    const float* bn1rv  = (const float*)d_in[24];

    const float* l1W = (const float*)d_in[25];
    const float* l1b = (const float*)d_in[26];
    const float* l2W = (const float*)d_in[27];
    const float* l2b = (const float*)d_in[28];

    // workspace layout (float units)
    float* ws   = (float*)d_ws;
    float* hT   = ws;                        // EHD*NE = 10,240,000
    float* msg  = ws + 10240000;             // NE*32  =  5,120,000
    float* x1   = ws + 15360000;             // NN*32  =    640,000
    float* x2   = ws + 16000000;             // NN*32  =    640,000
    float* gbuf = ws + 16640000;             // NG*32  =      2,048
    int* hist    = (int*)(ws + 16642048);    // NN
    int* rowptr  = (int*)(ws + 16662048);    // NN+1
    int* cursor  = (int*)(ws + 16682050);    // NN
    int* sortpos = (int*)(ws + 16702050);    // NE
    // total ~16.86M floats ~= 67.4 MB

    const dim3 egrid256(NE / 256, 2);
    const dim3 egrid64(NE / 64, 2);

    // zero gbuf + hist (contiguous 2048 + 20000 = 22048 elements)
    zero_kernel<<<87, 256, 0, stream>>>(gbuf, 22048);

    // CSR build (reused by both layers)
    hist_kernel<<<NE / 256, 256, 0, stream>>>(edst, hist);
    scan_kernel<<<1, 1024, 0, stream>>>(hist, rowptr, cursor);
    scatter_kernel<<<NE / 256, 256, 0, stream>>>(edst, cursor, sortpos);

    // layer 0
    edge_mlp_kernel<<<egrid256, 256, 0, stream>>>(eattr, c0W1, c0b1, hT);
    nnconv_kernel<<<egrid64, 64, 0, stream>>>(x, esrc, sortpos, hT, c0W2, c0b2, msg);
    node_update_kernel<<<NN * HD / 256, 256, 0, stream>>>(rowptr, msg, x, c0root, c0bias,
                                                          bn0g, bn0b, bn0rm, bn0rv, x1);
    // layer 1
    edge_mlp_kernel<<<egrid256, 256, 0, stream>>>(eattr, c1W1, c1b1, hT);
    nnconv_kernel<<<egrid64, 64, 0, stream>>>(x1, esrc, sortpos, hT, c1W2, c1b2, msg);
    node_update_kernel<<<NN * HD / 256, 256, 0, stream>>>(rowptr, msg, x1, c1root, c1bias,
                                                          bn1g, bn1b, bn1rm, bn1rv, x2);
    // pool + head
    pool_kernel<<<NN * HD / 256, 256, 0, stream>>>(x2, batch, gbuf);
    head_kernel<<<1, 64, 0, stream>>>(gbuf, l1W, l1b, l2W, l2b, (float*)d_out);
}

// Round 4
// 1027.320 us; speedup vs baseline: 1.9343x; 1.6028x over previous
//
#include <hip/hip_runtime.h>

#define NN   20000   // nodes
#define NE   160000  // edges
#define HD   32      // hidden / in dim
#define EFD  95      // edge feature dim
#define EHD  64      // edge hidden dim
#define NG   64      // graphs
#define EPSF 1e-5f

// ---------------------------------------------------------------- zero fill
__global__ __launch_bounds__(256) void zero_kernel(float* __restrict__ p, int n) {
    int i = blockIdx.x * 256 + threadIdx.x;
    if (i < n) p[i] = 0.f;
}

// ---------------------------------------------------------------- CSR build: histogram of dst
__global__ __launch_bounds__(256) void hist_kernel(const int* __restrict__ dst,
                                                   int* __restrict__ hist) {
    const int e = blockIdx.x * 256 + threadIdx.x;   // grid exactly NE/256
    atomicAdd(&hist[dst[e]], 1);
}

// ---------------------------------------------------------------- CSR build: exclusive scan (single block)
__global__ __launch_bounds__(1024) void scan_kernel(const int* __restrict__ hist,
                                                    int* __restrict__ rowptr,
                                                    int* __restrict__ cursor) {
    __shared__ int part[1024];
    const int t = threadIdx.x;
    const int base = t * 20;
    int s = 0;
    #pragma unroll
    for (int k = 0; k < 20; ++k) {
        const int idx = base + k;
        if (idx < NN) s += hist[idx];
    }
    part[t] = s;
    __syncthreads();
    for (int off = 1; off < 1024; off <<= 1) {
        int v = 0;
        if (t >= off) v = part[t - off];
        __syncthreads();
        if (t >= off) part[t] += v;
        __syncthreads();
    }
    int run = part[t] - s;   // exclusive offset for this chunk
    #pragma unroll
    for (int k = 0; k < 20; ++k) {
        const int idx = base + k;
        if (idx < NN) {
            rowptr[idx] = run;
            cursor[idx] = run;
            run += hist[idx];
        }
    }
    if (t == 0) rowptr[NN] = NE;
}

// ---------------------------------------------------------------- CSR build: scatter -> sortpos
__global__ __launch_bounds__(256) void scatter_kernel(const int* __restrict__ dst,
                                                      int* __restrict__ cursor,
                                                      int* __restrict__ sortpos) {
    const int e = blockIdx.x * 256 + threadIdx.x;
    sortpos[e] = atomicAdd(&cursor[dst[e]], 1);
}

// ---------------------------------------------------------------- edge MLP: hT[k][e] = relu(ea @ W1 + b1)
// Block 256 handles 128 edges. Stage ea rows through LDS with coalesced
// float4 reads (fixes 21x HBM over-fetch: lanes previously strided 380B).
// 2 threads/edge, each does 32 of 64 outputs; half is wave-uniform -> W1
// row address uniform -> s_load. LDS stride 95 == -1 mod 32: the read
// lds[el*95+j] lands 2 lanes/bank -> conflict-free.
__global__ __launch_bounds__(256) void edge_mlp_kernel(
    const float* __restrict__ ea,    // NE x 95
    const float* __restrict__ W1,    // 95 x 64
    const float* __restrict__ b1,    // 64
    float*       __restrict__ hT)    // EHD x NE (out, transposed)
{
    __shared__ float elds[128 * EFD];          // 48,640 B -> 3 blocks/CU
    const int tid = threadIdx.x;
    const int e0  = blockIdx.x * 128;          // grid exactly NE/128

    // coalesced stage: 3040 float4s (base is 16B aligned: 128*95*4 per block)
    const float4* s4 = reinterpret_cast<const float4*>(ea + (size_t)e0 * EFD);
    float4* d4 = reinterpret_cast<float4*>(elds);
    #pragma unroll
    for (int i = 0; i < 12; ++i) {
        const int idx = tid + i * 256;
        if (idx < (128 * EFD / 4)) d4[idx] = s4[idx];
    }
    __syncthreads();

    const int el = tid & 127;                  // edge within block
    const int hh = (tid >> 7) * 32;            // output half (wave-uniform)
    const int e  = e0 + el;

    float acc[32];
    #pragma unroll
    for (int k = 0; k < 32; ++k) acc[k] = b1[hh + k];

    const float* er = elds + el * EFD;
    #pragma unroll 5
    for (int j = 0; j < EFD; ++j) {
        const float ej = er[j];                // ds_read, 2 lanes/bank
        const float* w1r = W1 + j * EHD + hh;  // uniform -> s_load
        #pragma unroll
        for (int k = 0; k < 32; ++k)
            acc[k] = fmaf(ej, w1r[k], acc[k]);
    }

    #pragma unroll
    for (int k = 0; k < 32; ++k)
        hT[(hh + k) * NE + e] = fmaxf(acc[k], 0.f);   // coalesced across lanes
}

// ---------------------------------------------------------------- NNConv contraction, atomic-free
// grid (NE/64, 2), block 64. Thread computes 16 of 32 msg outputs for one
// edge, stores at dst-sorted slot sortpos[e]. W2/b2 uniform -> s_load.
__global__ __launch_bounds__(64) void nnconv_kernel(
    const float* __restrict__ xin,     // NN x 32
    const int*   __restrict__ src,     // NE
    const int*   __restrict__ sortpos, // NE
    const float* __restrict__ hT,      // EHD x NE (relu'd)
    const float* __restrict__ W2,      // 64 x 1024
    const float* __restrict__ b2,      // 1024
    float*       __restrict__ msg)     // NE x 32, dst-sorted rows
{
    const int e  = blockIdx.x * 64 + threadIdx.x;
    const int oh = blockIdx.y * 16;          // wave-uniform output-half select
    const int s  = src[e];
    const int sp = sortpos[e];

    float xs[HD];
    {
        const float* xr = xin + s * HD;
        #pragma unroll
        for (int i = 0; i < HD; i += 4) {
            const float4 v = *reinterpret_cast<const float4*>(xr + i);
            xs[i] = v.x; xs[i + 1] = v.y; xs[i + 2] = v.z; xs[i + 3] = v.w;
        }
    }

    float acc[16];
    #pragma unroll
    for (int o = 0; o < 16; ++o) acc[o] = 0.f;

    #pragma unroll 1
    for (int kh = 0; kh < EHD; ++kh) {
        const float hk = hT[kh * NE + e];              // coalesced
        const float* w2k = W2 + kh * (HD * HD) + oh;   // uniform -> s_load
        #pragma unroll
        for (int i = 0; i < HD; ++i) {
            const float p = hk * xs[i];
            #pragma unroll
            for (int o = 0; o < 16; ++o)
                acc[o] = fmaf(p, w2k[i * HD + o], acc[o]);
        }
    }

    #pragma unroll 1
    for (int i = 0; i < HD; ++i) {
        const float xi = xs[i];
        const float* b2r = b2 + i * HD + oh;     // uniform -> s_load
        #pragma unroll
        for (int o = 0; o < 16; ++o)
            acc[o] = fmaf(xi, b2r[o], acc[o]);
    }

    float* mr = msg + sp * HD + oh;
    #pragma unroll
    for (int q = 0; q < 4; ++q) {
        float4 v;
        v.x = acc[q * 4 + 0]; v.y = acc[q * 4 + 1];
        v.z = acc[q * 4 + 2]; v.w = acc[q * 4 + 3];
        *reinterpret_cast<float4*>(mr + q * 4) = v;
    }
}

// ---------------------------------------------------------------- fused CSR-reduce + root GEMV + BN + relu
__global__ __launch_bounds__(256) void node_update_kernel(
    const int*   __restrict__ rowptr, const float* __restrict__ msg,
    const float* __restrict__ xin,
    const float* __restrict__ root, const float* __restrict__ bias,
    const float* __restrict__ bg, const float* __restrict__ bb,
    const float* __restrict__ brm, const float* __restrict__ brv,
    float* __restrict__ xout)
{
    const int gid = blockIdx.x * 256 + threadIdx.x;   // grid = NN*32/256
    const int n = gid >> 5, o = gid & 31;

    float a = 0.f;
    const int j0 = rowptr[n], j1 = rowptr[n + 1];
    for (int j = j0; j < j1; ++j)                     // mean 8 iters, coalesced in o
        a += msg[j * HD + o];

    const float* xr = xin + n * HD;
    #pragma unroll
    for (int i = 0; i < HD; ++i)
        a = fmaf(xr[i], root[i * HD + o], a);
    a += bias[o];
    a = (a - brm[o]) * rsqrtf(brv[o] + EPSF) * bg[o] + bb[o];
    xout[gid] = fmaxf(a, 0.f);
}

// ---------------------------------------------------------------- segment max pool (x >= 0 after relu; g zero-init)
__global__ __launch_bounds__(256) void pool_kernel(
    const float* __restrict__ x, const int* __restrict__ batch,
    float* __restrict__ g)
{
    const int gid = blockIdx.x * 256 + threadIdx.x;
    const int n = gid >> 5, o = gid & 31;
    const float v = x[gid];
    atomicMax(reinterpret_cast<int*>(g) + batch[n] * HD + o, __float_as_int(v));
}

// ---------------------------------------------------------------- MLP head
__global__ __launch_bounds__(64) void head_kernel(
    const float* __restrict__ g, const float* __restrict__ l1W,
    const float* __restrict__ l1b, const float* __restrict__ l2W,
    const float* __restrict__ l2b, float* __restrict__ out)
{
    const int gr = threadIdx.x;
    const float* grow = g + gr * HD;
    float hv[HD];
    #pragma unroll
    for (int o = 0; o < HD; ++o) hv[o] = l1b[o];
    #pragma unroll
    for (int i = 0; i < HD; ++i) {
        const float gi = grow[i];
        #pragma unroll
        for (int o = 0; o < HD; ++o)
            hv[o] = fmaf(gi, l1W[i * HD + o], hv[o]);
    }
    float o0 = l2b[0], o1 = l2b[1];
    #pragma unroll
    for (int o = 0; o < HD; ++o) {
        const float r = fmaxf(hv[o], 0.f);
        o0 = fmaf(r, l2W[o * 2 + 0], o0);
        o1 = fmaf(r, l2W[o * 2 + 1], o1);
    }
    out[gr * 2 + 0] = o0;
    out[gr * 2 + 1] = o1;
}

// ---------------------------------------------------------------- launcher
extern "C" void kernel_launch(void* const* d_in, const int* in_sizes, int n_in,
                              void* d_out, int out_size, void* d_ws, size_t ws_size,
                              hipStream_t stream)
{
    const float* x     = (const float*)d_in[0];
    const int*   esrc  = (const int*)  d_in[1];
    const int*   edst  = (const int*)  d_in[2];
    const float* eattr = (const float*)d_in[3];
    const int*   batch = (const int*)  d_in[4];

    const float* c0W1   = (const float*)d_in[5];
    const float* c0b1   = (const float*)d_in[6];
    const float* c0W2   = (const float*)d_in[7];
    const float* c0b2   = (const float*)d_in[8];
    const float* c0root = (const float*)d_in[9];
    const float* c0bias = (const float*)d_in[10];
    const float* bn0g   = (const float*)d_in[11];
    const float* bn0b   = (const float*)d_in[12];
    const float* bn0rm  = (const float*)d_in[13];
    const float* bn0rv  = (const float*)d_in[14];

    const float* c1W1   = (const float*)d_in[15];
    const float* c1b1   = (const float*)d_in[16];
    const float* c1W2   = (const float*)d_in[17];
    const float* c1b2   = (const float*)d_in[18];
    const float* c1root = (const float*)d_in[19];
    const float* c1bias = (const float*)d_in[20];
    const float* bn1g   = (const float*)d_in[21];
    const float* bn1b   = (const float*)d_in[22];
    const float* bn1rm  = (const float*)d_in[23];
    const float* bn1rv  = (const float*)d_in[24];

    const float* l1W = (const float*)d_in[25];
    const float* l1b = (const float*)d_in[26];
    const float* l2W = (const float*)d_in[27];
    const float* l2b = (const float*)d_in[28];

    // workspace layout (float units)
    float* ws   = (float*)d_ws;
    float* hT   = ws;                        // EHD*NE = 10,240,000
    float* msg  = ws + 10240000;             // NE*32  =  5,120,000
    float* x1   = ws + 15360000;             // NN*32  =    640,000
    float* x2   = ws + 16000000;             // NN*32  =    640,000
    float* gbuf = ws + 16640000;             // NG*32  =      2,048
    int* hist    = (int*)(ws + 16642048);    // NN
    int* rowptr  = (int*)(ws + 16662048);    // NN+1
    int* cursor  = (int*)(ws + 16682050);    // NN
    int* sortpos = (int*)(ws + 16702050);    // NE
    // total ~16.86M floats ~= 67.4 MB

    const dim3 egrid64(NE / 64, 2);

    // zero gbuf + hist (contiguous 2048 + 20000 = 22048 elements)
    zero_kernel<<<87, 256, 0, stream>>>(gbuf, 22048);

    // CSR build (reused by both layers)
    hist_kernel<<<NE / 256, 256, 0, stream>>>(edst, hist);
    scan_kernel<<<1, 1024, 0, stream>>>(hist, rowptr, cursor);
    scatter_kernel<<<NE / 256, 256, 0, stream>>>(edst, cursor, sortpos);

    // layer 0
    edge_mlp_kernel<<<NE / 128, 256, 0, stream>>>(eattr, c0W1, c0b1, hT);
    nnconv_kernel<<<egrid64, 64, 0, stream>>>(x, esrc, sortpos, hT, c0W2, c0b2, msg);
    node_update_kernel<<<NN * HD / 256, 256, 0, stream>>>(rowptr, msg, x, c0root, c0bias,
                                                          bn0g, bn0b, bn0rm, bn0rv, x1);
    // layer 1
    edge_mlp_kernel<<<NE / 128, 256, 0, stream>>>(eattr, c1W1, c1b1, hT);
    nnconv_kernel<<<egrid64, 64, 0, stream>>>(x1, esrc, sortpos, hT, c1W2, c1b2, msg);
    node_update_kernel<<<NN * HD / 256, 256, 0, stream>>>(rowptr, msg, x1, c1root, c1bias,
                                                          bn1g, bn1b, bn1rm, bn1rv, x2);
    // pool + head
    pool_kernel<<<NN * HD / 256, 256, 0, stream>>>(x2, batch, gbuf);
    head_kernel<<<1, 64, 0, stream>>>(gbuf, l1W, l1b, l2W, l2b, (float*)d_out);
}

// Round 5
// 814.276 us; speedup vs baseline: 2.4403x; 1.2616x over previous
//
#include <hip/hip_runtime.h>

#define NN   20000   // nodes
#define NE   160000  // edges
#define HD   32      // hidden / in dim
#define EFD  95      // edge feature dim
#define EHD  64      // edge hidden dim
#define NG   64      // graphs
#define EPSF 1e-5f

// ---------------------------------------------------------------- zero fill
__global__ __launch_bounds__(256) void zero_kernel(float* __restrict__ p, int n) {
    int i = blockIdx.x * 256 + threadIdx.x;
    if (i < n) p[i] = 0.f;
}

// ---------------------------------------------------------------- CSR build: histogram
__global__ __launch_bounds__(256) void hist_kernel(const int* __restrict__ idx,
                                                   int* __restrict__ hist) {
    const int e = blockIdx.x * 256 + threadIdx.x;   // grid exactly NE/256
    atomicAdd(&hist[idx[e]], 1);
}

// ---------------------------------------------------------------- CSR build: exclusive scan (single block)
__global__ __launch_bounds__(1024) void scan_kernel(const int* __restrict__ hist,
                                                    int* __restrict__ rowptr,
                                                    int* __restrict__ cursor) {
    __shared__ int part[1024];
    const int t = threadIdx.x;
    const int base = t * 20;
    int s = 0;
    #pragma unroll
    for (int k = 0; k < 20; ++k) {
        const int idx = base + k;
        if (idx < NN) s += hist[idx];
    }
    part[t] = s;
    __syncthreads();
    for (int off = 1; off < 1024; off <<= 1) {
        int v = 0;
        if (t >= off) v = part[t - off];
        __syncthreads();
        if (t >= off) part[t] += v;
        __syncthreads();
    }
    int run = part[t] - s;   // exclusive offset for this chunk
    #pragma unroll
    for (int k = 0; k < 20; ++k) {
        const int idx = base + k;
        if (idx < NN) {
            rowptr[idx] = run;
            cursor[idx] = run;
            run += hist[idx];
        }
    }
    if (t == 0) rowptr[NN] = NE;
}

// ---------------------------------------------------------------- dst scatter -> sortpos_d
__global__ __launch_bounds__(256) void scatter_dst_kernel(const int* __restrict__ dst,
                                                          int* __restrict__ cursor,
                                                          int* __restrict__ sortpos) {
    const int e = blockIdx.x * 256 + threadIdx.x;
    sortpos[e] = atomicAdd(&cursor[dst[e]], 1);
}

// ---------------------------------------------------------------- src scatter -> ssorted/wpos/psrc
__global__ __launch_bounds__(256) void scatter_src_kernel(const int* __restrict__ src,
                                                          const int* __restrict__ sortpos_d,
                                                          int* __restrict__ cursor,
                                                          int* __restrict__ ssorted,
                                                          int* __restrict__ wpos,
                                                          int* __restrict__ psrc) {
    const int e = blockIdx.x * 256 + threadIdx.x;
    const int s = src[e];
    const int pos = atomicAdd(&cursor[s], 1);
    ssorted[pos] = s;            // src node of sorted slot
    wpos[pos]    = sortpos_d[e]; // where slot's msg goes (dst-sorted)
    psrc[e]      = pos;          // where edge e's h row goes (src-sorted)
}

// ---------------------------------------------------------------- edge MLP (fallback, hT output)
__global__ __launch_bounds__(256) void edge_mlp_kernel(
    const float* __restrict__ ea, const float* __restrict__ W1,
    const float* __restrict__ b1, float* __restrict__ hT)   // EHD x NE
{
    __shared__ float elds[128 * EFD];
    const int tid = threadIdx.x;
    const int e0  = blockIdx.x * 128;
    const float4* s4 = reinterpret_cast<const float4*>(ea + (size_t)e0 * EFD);
    float4* d4 = reinterpret_cast<float4*>(elds);
    #pragma unroll
    for (int i = 0; i < 12; ++i) {
        const int idx = tid + i * 256;
        if (idx < (128 * EFD / 4)) d4[idx] = s4[idx];
    }
    __syncthreads();
    const int el = tid & 127;
    const int hh = (tid >> 7) * 32;
    const int e  = e0 + el;
    float acc[32];
    #pragma unroll
    for (int k = 0; k < 32; ++k) acc[k] = b1[hh + k];
    const float* er = elds + el * EFD;
    #pragma unroll 5
    for (int j = 0; j < EFD; ++j) {
        const float ej = er[j];
        const float* w1r = W1 + j * EHD + hh;
        #pragma unroll
        for (int k = 0; k < 32; ++k)
            acc[k] = fmaf(ej, w1r[k], acc[k]);
    }
    #pragma unroll
    for (int k = 0; k < 32; ++k)
        hT[(hh + k) * NE + e] = fmaxf(acc[k], 0.f);
}

// ---------------------------------------------------------------- edge MLP (src-sorted row-major output)
__global__ __launch_bounds__(256) void edge_mlp_sorted_kernel(
    const float* __restrict__ ea, const float* __restrict__ W1,
    const float* __restrict__ b1, const int* __restrict__ psrc,
    float* __restrict__ hs)   // NE x 64, rows at src-sorted slots
{
    __shared__ float elds[128 * EFD];
    const int tid = threadIdx.x;
    const int e0  = blockIdx.x * 128;
    const float4* s4 = reinterpret_cast<const float4*>(ea + (size_t)e0 * EFD);
    float4* d4 = reinterpret_cast<float4*>(elds);
    #pragma unroll
    for (int i = 0; i < 12; ++i) {
        const int idx = tid + i * 256;
        if (idx < (128 * EFD / 4)) d4[idx] = s4[idx];
    }
    __syncthreads();
    const int el = tid & 127;
    const int hh = (tid >> 7) * 32;
    const int e  = e0 + el;
    float acc[32];
    #pragma unroll
    for (int k = 0; k < 32; ++k) acc[k] = b1[hh + k];
    const float* er = elds + el * EFD;
    #pragma unroll 5
    for (int j = 0; j < EFD; ++j) {
        const float ej = er[j];
        const float* w1r = W1 + j * EHD + hh;
        #pragma unroll
        for (int k = 0; k < 32; ++k)
            acc[k] = fmaf(ej, w1r[k], acc[k]);
    }
    float* hr = hs + (size_t)psrc[e] * EHD + hh;    // 128B aligned
    #pragma unroll
    for (int k4 = 0; k4 < 8; ++k4) {
        float4 v;
        v.x = fmaxf(acc[k4 * 4 + 0], 0.f);
        v.y = fmaxf(acc[k4 * 4 + 1], 0.f);
        v.z = fmaxf(acc[k4 * 4 + 2], 0.f);
        v.w = fmaxf(acc[k4 * 4 + 3], 0.f);
        *reinterpret_cast<float4*>(hr + k4 * 4) = v;
    }
}

// ---------------------------------------------------------------- T = x @ W2r : T[n, kh*32+o] = sum_i x[n,i]*W2[kh][i*32+o]
// grid (NN/8, 8), block 256. Thread owns one c=kh*32+o, 8 nodes.
// W2 loads coalesced (o across lanes); x row uniform -> s_load.
__global__ __launch_bounds__(256) void tmat_kernel(
    const float* __restrict__ xin,   // NN x 32
    const float* __restrict__ W2,    // 64 x 1024
    float*       __restrict__ T)     // NN x 2048
{
    const int nb = blockIdx.x * 8;
    const int c  = blockIdx.y * 256 + threadIdx.x;   // 0..2047
    const int kh = c >> 5, o = c & 31;

    float w[32];
    const float* wp = W2 + kh * 1024 + o;
    #pragma unroll
    for (int i = 0; i < 32; ++i) w[i] = wp[i * 32];  // 128B coalesced / group

    #pragma unroll
    for (int nj = 0; nj < 8; ++nj) {
        const float* xr = xin + (nb + nj) * HD;      // uniform -> s_load
        float a0 = 0.f, a1 = 0.f;
        #pragma unroll
        for (int i = 0; i < 32; i += 2) {
            a0 = fmaf(xr[i],     w[i],     a0);
            a1 = fmaf(xr[i + 1], w[i + 1], a1);
        }
        T[(size_t)(nb + nj) * 2048 + c] = a0 + a1;   // 1KB coalesced / node
    }
}

// ---------------------------------------------------------------- bvec[n,o] = sum_i x[n,i]*b2[i*32+o]
__global__ __launch_bounds__(256) void bvec_kernel(
    const float* __restrict__ xin, const float* __restrict__ b2,
    float* __restrict__ bv)
{
    const int gid = blockIdx.x * 256 + threadIdx.x;  // NN*32/256
    const int n = gid >> 5, o = gid & 31;
    const float* xr = xin + n * HD;
    float a = 0.f;
    #pragma unroll
    for (int i = 0; i < 32; ++i)
        a = fmaf(xr[i], b2[i * HD + o], a);
    bv[gid] = a;
}

// ---------------------------------------------------------------- per-edge contraction over kh, src-sorted
// grid NE/8, block 256 = 8 slots x 32 o. msg written at dst-sorted slot.
__global__ __launch_bounds__(256) void emsg_kernel(
    const int*   __restrict__ ssorted, const int* __restrict__ wpos,
    const float* __restrict__ hs,    // NE x 64, src-sorted rows
    const float* __restrict__ T,     // NN x 2048
    const float* __restrict__ bv,    // NN x 32
    float*       __restrict__ msg)   // NE x 32, dst-sorted rows
{
    __shared__ float hl[8 * EHD];
    const int tid = threadIdx.x;
    const int p0  = blockIdx.x * 8;

    if (tid < 128)   // stage 8 h rows (2KB contiguous, coalesced)
        reinterpret_cast<float4*>(hl)[tid] =
            reinterpret_cast<const float4*>(hs + (size_t)p0 * EHD)[tid];
    __syncthreads();

    const int sl = tid >> 5, o = tid & 31;
    const int p  = p0 + sl;
    const int s  = ssorted[p];
    const int wp = wpos[p];

    float hreg[EHD];
    #pragma unroll
    for (int q = 0; q < 16; ++q) {   // broadcast ds_read_b128
        const float4 v = reinterpret_cast<const float4*>(hl + sl * EHD)[q];
        hreg[q * 4] = v.x; hreg[q * 4 + 1] = v.y;
        hreg[q * 4 + 2] = v.z; hreg[q * 4 + 3] = v.w;
    }

    const float* tr = T + (size_t)s * 2048 + o;
    float a0 = bv[s * HD + o], a1 = 0.f;
    #pragma unroll
    for (int kh = 0; kh < EHD; kh += 2) {
        a0 = fmaf(hreg[kh],     tr[kh * 32],       a0);   // 128B coalesced/group
        a1 = fmaf(hreg[kh + 1], tr[(kh + 1) * 32], a1);
    }
    msg[(size_t)wp * HD + o] = a0 + a1;
}

// ---------------------------------------------------------------- NNConv contraction (fallback path)
__global__ __launch_bounds__(64) void nnconv_kernel(
    const float* __restrict__ xin, const int* __restrict__ src,
    const int* __restrict__ sortpos, const float* __restrict__ hT,
    const float* __restrict__ W2, const float* __restrict__ b2,
    float* __restrict__ msg)
{
    const int e  = blockIdx.x * 64 + threadIdx.x;
    const int oh = blockIdx.y * 16;
    const int s  = src[e];
    const int sp = sortpos[e];
    float xs[HD];
    {
        const float* xr = xin + s * HD;
        #pragma unroll
        for (int i = 0; i < HD; i += 4) {
            const float4 v = *reinterpret_cast<const float4*>(xr + i);
            xs[i] = v.x; xs[i + 1] = v.y; xs[i + 2] = v.z; xs[i + 3] = v.w;
        }
    }
    float acc[16];
    #pragma unroll
    for (int o = 0; o < 16; ++o) acc[o] = 0.f;
    #pragma unroll 1
    for (int kh = 0; kh < EHD; ++kh) {
        const float hk = hT[kh * NE + e];
        const float* w2k = W2 + kh * (HD * HD) + oh;
        #pragma unroll
        for (int i = 0; i < HD; ++i) {
            const float p = hk * xs[i];
            #pragma unroll
            for (int o = 0; o < 16; ++o)
                acc[o] = fmaf(p, w2k[i * HD + o], acc[o]);
        }
    }
    #pragma unroll 1
    for (int i = 0; i < HD; ++i) {
        const float xi = xs[i];
        const float* b2r = b2 + i * HD + oh;
        #pragma unroll
        for (int o = 0; o < 16; ++o)
            acc[o] = fmaf(xi, b2r[o], acc[o]);
    }
    float* mr = msg + sp * HD + oh;
    #pragma unroll
    for (int q = 0; q < 4; ++q) {
        float4 v;
        v.x = acc[q * 4 + 0]; v.y = acc[q * 4 + 1];
        v.z = acc[q * 4 + 2]; v.w = acc[q * 4 + 3];
        *reinterpret_cast<float4*>(mr + q * 4) = v;
    }
}

// ---------------------------------------------------------------- fused CSR-reduce + root GEMV + BN + relu
__global__ __launch_bounds__(256) void node_update_kernel(
    const int*   __restrict__ rowptr, const float* __restrict__ msg,
    const float* __restrict__ xin,
    const float* __restrict__ root, const float* __restrict__ bias,
    const float* __restrict__ bg, const float* __restrict__ bb,
    const float* __restrict__ brm, const float* __restrict__ brv,
    float* __restrict__ xout)
{
    const int gid = blockIdx.x * 256 + threadIdx.x;
    const int n = gid >> 5, o = gid & 31;
    float a = 0.f;
    const int j0 = rowptr[n], j1 = rowptr[n + 1];
    for (int j = j0; j < j1; ++j)
        a += msg[j * HD + o];
    const float* xr = xin + n * HD;
    #pragma unroll
    for (int i = 0; i < HD; ++i)
        a = fmaf(xr[i], root[i * HD + o], a);
    a += bias[o];
    a = (a - brm[o]) * rsqrtf(brv[o] + EPSF) * bg[o] + bb[o];
    xout[gid] = fmaxf(a, 0.f);
}

// ---------------------------------------------------------------- segment max pool
__global__ __launch_bounds__(256) void pool_kernel(
    const float* __restrict__ x, const int* __restrict__ batch,
    float* __restrict__ g)
{
    const int gid = blockIdx.x * 256 + threadIdx.x;
    const int n = gid >> 5, o = gid & 31;
    const float v = x[gid];
    atomicMax(reinterpret_cast<int*>(g) + batch[n] * HD + o, __float_as_int(v));
}

// ---------------------------------------------------------------- MLP head
__global__ __launch_bounds__(64) void head_kernel(
    const float* __restrict__ g, const float* __restrict__ l1W,
    const float* __restrict__ l1b, const float* __restrict__ l2W,
    const float* __restrict__ l2b, float* __restrict__ out)
{
    const int gr = threadIdx.x;
    const float* grow = g + gr * HD;
    float hv[HD];
    #pragma unroll
    for (int o = 0; o < HD; ++o) hv[o] = l1b[o];
    #pragma unroll
    for (int i = 0; i < HD; ++i) {
        const float gi = grow[i];
        #pragma unroll
        for (int o = 0; o < HD; ++o)
            hv[o] = fmaf(gi, l1W[i * HD + o], hv[o]);
    }
    float o0 = l2b[0], o1 = l2b[1];
    #pragma unroll
    for (int o = 0; o < HD; ++o) {
        const float r = fmaxf(hv[o], 0.f);
        o0 = fmaf(r, l2W[o * 2 + 0], o0);
        o1 = fmaf(r, l2W[o * 2 + 1], o1);
    }
    out[gr * 2 + 0] = o0;
    out[gr * 2 + 1] = o1;
}

// ---------------------------------------------------------------- launcher
extern "C" void kernel_launch(void* const* d_in, const int* in_sizes, int n_in,
                              void* d_out, int out_size, void* d_ws, size_t ws_size,
                              hipStream_t stream)
{
    const float* x     = (const float*)d_in[0];
    const int*   esrc  = (const int*)  d_in[1];
    const int*   edst  = (const int*)  d_in[2];
    const float* eattr = (const float*)d_in[3];
    const int*   batch = (const int*)  d_in[4];

    const float* c0W1   = (const float*)d_in[5];
    const float* c0b1   = (const float*)d_in[6];
    const float* c0W2   = (const float*)d_in[7];
    const float* c0b2   = (const float*)d_in[8];
    const float* c0root = (const float*)d_in[9];
    const float* c0bias = (const float*)d_in[10];
    const float* bn0g   = (const float*)d_in[11];
    const float* bn0b   = (const float*)d_in[12];
    const float* bn0rm  = (const float*)d_in[13];
    const float* bn0rv  = (const float*)d_in[14];

    const float* c1W1   = (const float*)d_in[15];
    const float* c1b1   = (const float*)d_in[16];
    const float* c1W2   = (const float*)d_in[17];
    const float* c1b2   = (const float*)d_in[18];
    const float* c1root = (const float*)d_in[19];
    const float* c1bias = (const float*)d_in[20];
    const float* bn1g   = (const float*)d_in[21];
    const float* bn1b   = (const float*)d_in[22];
    const float* bn1rm  = (const float*)d_in[23];
    const float* bn1rv  = (const float*)d_in[24];

    const float* l1W = (const float*)d_in[25];
    const float* l1b = (const float*)d_in[26];
    const float* l2W = (const float*)d_in[27];
    const float* l2b = (const float*)d_in[28];

    // ---- workspace layout (float units) ----
    float* ws   = (float*)d_ws;
    float* hbuf = ws;                        // NE*64 = 10,240,000 (hs or hT)
    float* msg  = ws + 10240000;             // NE*32 =  5,120,000
    float* x1   = ws + 15360000;             // 640,000
    float* x2   = ws + 16000000;             // 640,000
    float* gbuf = ws + 16640000;             // 2,048
    int* hist_d    = (int*)(ws + 16642048);  // 20,000
    int* hist_s    = (int*)(ws + 16662048);  // 20,000  (zero span: gbuf..hist_s = 42,048)
    int* rowptr_d  = (int*)(ws + 16682048);  // 20,001
    int* cursor_d  = (int*)(ws + 16702049);  // 20,000
    int* sortpos_d = (int*)(ws + 16722049);  // 160,000
    int* rowptr_s  = (int*)(ws + 16882049);  // 20,001
    int* cursor_s  = (int*)(ws + 16902050);  // 20,000
    int* ssorted   = (int*)(ws + 16922050);  // 160,000
    int* wpos      = (int*)(ws + 17082050);  // 160,000
    int* psrc      = (int*)(ws + 17242050);  // 160,000
    float* bv      = ws + 17402050;          // 640,000
    float* T       = ws + 18042050;          // 40,960,000
    const size_t NEED_NEW = (size_t)59002050 * 4;   // ~236 MB
    const bool use_fast = (ws_size >= NEED_NEW);

    // zero gbuf + hist_d + hist_s (contiguous 42,048 = 164.25*256)
    zero_kernel<<<165, 256, 0, stream>>>(gbuf, 42048);

    // dst-CSR (both paths)
    hist_kernel<<<NE / 256, 256, 0, stream>>>(edst, hist_d);
    scan_kernel<<<1, 1024, 0, stream>>>(hist_d, rowptr_d, cursor_d);
    scatter_dst_kernel<<<NE / 256, 256, 0, stream>>>(edst, cursor_d, sortpos_d);

    if (use_fast) {
        // src-CSR
        hist_kernel<<<NE / 256, 256, 0, stream>>>(esrc, hist_s);
        scan_kernel<<<1, 1024, 0, stream>>>(hist_s, rowptr_s, cursor_s);
        scatter_src_kernel<<<NE / 256, 256, 0, stream>>>(esrc, sortpos_d, cursor_s,
                                                         ssorted, wpos, psrc);
        const dim3 tgrid(NN / 8, 8);
        // layer 0
        bvec_kernel<<<NN * HD / 256, 256, 0, stream>>>(x, c0b2, bv);
        tmat_kernel<<<tgrid, 256, 0, stream>>>(x, c0W2, T);
        edge_mlp_sorted_kernel<<<NE / 128, 256, 0, stream>>>(eattr, c0W1, c0b1, psrc, hbuf);
        emsg_kernel<<<NE / 8, 256, 0, stream>>>(ssorted, wpos, hbuf, T, bv, msg);
        node_update_kernel<<<NN * HD / 256, 256, 0, stream>>>(rowptr_d, msg, x, c0root, c0bias,
                                                              bn0g, bn0b, bn0rm, bn0rv, x1);
        // layer 1
        bvec_kernel<<<NN * HD / 256, 256, 0, stream>>>(x1, c1b2, bv);
        tmat_kernel<<<tgrid, 256, 0, stream>>>(x1, c1W2, T);
        edge_mlp_sorted_kernel<<<NE / 128, 256, 0, stream>>>(eattr, c1W1, c1b1, psrc, hbuf);
        emsg_kernel<<<NE / 8, 256, 0, stream>>>(ssorted, wpos, hbuf, T, bv, msg);
        node_update_kernel<<<NN * HD / 256, 256, 0, stream>>>(rowptr_d, msg, x1, c1root, c1bias,
                                                              bn1g, bn1b, bn1rm, bn1rv, x2);
    } else {
        // fallback: round-4 structure (fits in ~70 MB)
        const dim3 egrid64(NE / 64, 2);
        edge_mlp_kernel<<<NE / 128, 256, 0, stream>>>(eattr, c0W1, c0b1, hbuf);
        nnconv_kernel<<<egrid64, 64, 0, stream>>>(x, esrc, sortpos_d, hbuf, c0W2, c0b2, msg);
        node_update_kernel<<<NN * HD / 256, 256, 0, stream>>>(rowptr_d, msg, x, c0root, c0bias,
                                                              bn0g, bn0b, bn0rm, bn0rv, x1);
        edge_mlp_kernel<<<NE / 128, 256, 0, stream>>>(eattr, c1W1, c1b1, hbuf);
        nnconv_kernel<<<egrid64, 64, 0, stream>>>(x1, esrc, sortpos_d, hbuf, c1W2, c1b2, msg);
        node_update_kernel<<<NN * HD / 256, 256, 0, stream>>>(rowptr_d, msg, x1, c1root, c1bias,
                                                              bn1g, bn1b, bn1rm, bn1rv, x2);
    }

    // pool + head
    pool_kernel<<<NN * HD / 256, 256, 0, stream>>>(x2, batch, gbuf);
    head_kernel<<<1, 64, 0, stream>>>(gbuf, l1W, l1b, l2W, l2b, (float*)d_out);
}